// Round 12
// baseline (132.103 us; speedup 1.0000x reference)
//
#include <hip/hip_runtime.h>
#include <stdint.h>

typedef __attribute__((ext_vector_type(8))) short  bf16x8;
typedef __attribute__((ext_vector_type(4))) short  short4v;
typedef __attribute__((ext_vector_type(4))) float  f32x4;
typedef __attribute__((ext_vector_type(4))) float  float4v;

__device__ __forceinline__ unsigned short f2bf(float f) {
  unsigned int u = __builtin_bit_cast(unsigned int, f);
  u += 0x7FFFu + ((u >> 16) & 1u);          // round-to-nearest-even
  return (unsigned short)(u >> 16);
}
__device__ __forceinline__ float bf2f(unsigned short u) {
  return __builtin_bit_cast(float, (unsigned int)u << 16);
}

__device__ __forceinline__ void async_ld16(const void* g, void* l) {
  __builtin_amdgcn_global_load_lds(
      (const __attribute__((address_space(1))) void*)g,
      (__attribute__((address_space(3))) void*)l,
      16, 0, 0);
}

#define SB()  __builtin_amdgcn_sched_barrier(0)
#define BAR() __builtin_amdgcn_s_barrier()

// ----------------------------------------------------------- fused prep ----
__global__ __launch_bounds__(256) void prep(
    const float* __restrict__ x, const float* __restrict__ Wqkv,
    const float* __restrict__ Wproj,
    unsigned short* __restrict__ xb, unsigned short* __restrict__ wqkvT,
    unsigned short* __restrict__ wprojT) {
  __shared__ float tile[32][33];
  const int b = blockIdx.x, tid = threadIdx.x;
  if (b < 8192) {
    int i = b * 256 + tid;
    float4v v = *(const float4v*)(x + (size_t)i * 4);
    short4v o;
    o[0] = (short)f2bf(v[0]); o[1] = (short)f2bf(v[1]);
    o[2] = (short)f2bf(v[2]); o[3] = (short)f2bf(v[3]);
    *(short4v*)(xb + (size_t)i * 4) = o;
    return;
  }
  const float* in; unsigned short* out; int R, C, bx, by;
  if (b < 11264) { int t = b - 8192;  in = Wqkv;  out = wqkvT;  R = 1024; C = 3072; bx = t % 96; by = t / 96; }
  else           { int t = b - 11264; in = Wproj; out = wprojT; R = 1024; C = 1024; bx = t & 31; by = t >> 5; }
  const int tx = tid & 31, ty = tid >> 5;
  const int c0 = bx * 32, r0 = by * 32;
  #pragma unroll
  for (int rr = ty; rr < 32; rr += 8)
    tile[rr][tx] = in[(size_t)(r0 + rr) * C + c0 + tx];
  __syncthreads();
  #pragma unroll
  for (int cc = ty; cc < 32; cc += 8)
    out[(size_t)(c0 + cc) * R + r0 + tx] = f2bf(tile[tx][cc]);
}

// ------------------- 128x256-tile GEMM, 3 barriers/tile (grouped-B) --------
// C[M,N] = A[M,K](lda) * BTg[N,K]^T where BTg = BT + (bm>>10)*gstride.
// panels/buf = {B0,B1,A}; 6 slots = 96KB; 8 waves, wave tile 64x64.
// Proven schedule (R7-R11): RD burst -> BAR -> lgkm(0) -> 16 MFMA (x2 phases),
// tile-end burst stage t+2, counted vmcnt(6), publish barrier.
template<int BF16_OUT>
__global__ __launch_bounds__(512, 1) void gemm128(
    const unsigned short* __restrict__ A, int lda,
    const unsigned short* __restrict__ BT, size_t gstride,
    void* __restrict__ Cout, const float* __restrict__ bias,
    int ldc, int K) {
  constexpr int PAN = 16384;
  __shared__ __align__(16) char lds[6 * PAN];      // 96 KiB
  const int tid = threadIdx.x;
  const int ln = tid & 63, w = tid >> 6;
  const int lr = ln & 15, lq = ln >> 4;
  const int wm = w >> 2, wn = w & 3;

  int wid = blockIdx.y * gridDim.x + blockIdx.x;
  const int nwg = gridDim.x * gridDim.y;
  { const int q = nwg >> 3; wid = (wid & 7) * q + (wid >> 3); }
  const int bm = (wid / gridDim.x) * 128, bn = (wid % gridDim.x) * 256;

  const int srow = tid >> 3;
  const int csw = ((tid & 7) ^ (srow & 7)) * 8;
  const unsigned short* BTg = BT + (size_t)(bm >> 10) * gstride;
  const unsigned short* rB0 = BTg + (size_t)(bn + srow) * K + csw;
  const unsigned short* rB1 = rB0 + (size_t)128 * K;
  const unsigned short* rA0 = A + (size_t)(bm + srow) * lda + csw;
  const size_t rowB = (size_t)64 * K;
  const size_t rowA = (size_t)64 * lda;
  char* ldst = lds + tid * 16;

#define STGB(slot, src, t) do {                                              \
    async_ld16((src) + (size_t)(t) * 64,        ldst + (slot) * PAN);        \
    async_ld16((src) + (size_t)(t) * 64 + rowB, ldst + (slot) * PAN + 8192); \
  } while (0)
#define STGA(slot, src, t) do {                                              \
    async_ld16((src) + (size_t)(t) * 64,        ldst + (slot) * PAN);        \
    async_ld16((src) + (size_t)(t) * 64 + rowA, ldst + (slot) * PAN + 8192); \
  } while (0)

  const int sw0 = ((0 + lq) ^ (lr & 7)) * 16;
  const int sw1 = ((4 + lq) ^ (lr & 7)) * 16;
  const char* Arow = lds + (wm * 64 + lr) * 128;
  const char* Brow = lds + ((wn & 1) * 64 + lr) * 128;

  bf16x8 a[4], b[4];
  f32x4 acc[4][4] = {};

#define RD(ph_sw, Ap, Bp)                                                    \
    _Pragma("unroll")                                                        \
    for (int nf = 0; nf < 4; ++nf) b[nf] = *(const bf16x8*)((Bp) + nf * 2048 + (ph_sw)); \
    _Pragma("unroll")                                                        \
    for (int fi = 0; fi < 4; ++fi) a[fi] = *(const bf16x8*)((Ap) + fi * 2048 + (ph_sw));
#define MM16()                                                               \
    __builtin_amdgcn_s_setprio(1);                                           \
    _Pragma("unroll")                                                        \
    for (int fi = 0; fi < 4; ++fi)                                           \
      _Pragma("unroll")                                                      \
      for (int nf = 0; nf < 4; ++nf)                                         \
        acc[fi][nf] = __builtin_amdgcn_mfma_f32_16x16x32_bf16(a[fi], b[nf], acc[fi][nf], 0, 0, 0); \
    __builtin_amdgcn_s_setprio(0);

  STGB(0, rB0, 0); STGB(1, rB1, 0); STGA(2, rA0, 0);
  STGB(3, rB0, 1); STGB(4, rB1, 1); STGA(5, rA0, 1);
  asm volatile("s_waitcnt vmcnt(6)" ::: "memory");
  SB(); BAR(); SB();

  const int NT = K / 64;
  for (int t = 0; t < NT; ++t) {
    const int par = (t & 1) * 3;
    const char* Ap = Arow + (par + 2) * PAN;
    const char* Bp = Brow + (par + (wn >> 1)) * PAN;
    // phase 0 (k 0..31): open MFMA (no post barrier)
    RD(sw0, Ap, Bp);
    SB(); BAR();
    asm volatile("s_waitcnt lgkmcnt(0)" ::: "memory");
    SB();
    MM16();
    // phase 1 (k 32..63)
    RD(sw1, Ap, Bp);
    SB(); BAR();
    asm volatile("s_waitcnt lgkmcnt(0)" ::: "memory");
    SB();
    MM16();
    // tile end: stage t+2 into par slots; counted drain; publish
    if (t + 2 < NT) {
      STGB(par + 0, rB0, t + 2); STGB(par + 1, rB1, t + 2); STGA(par + 2, rA0, t + 2);
      asm volatile("s_waitcnt vmcnt(6)" ::: "memory");
    } else if (t == NT - 2) {
      asm volatile("s_waitcnt vmcnt(0)" ::: "memory");
    }
    SB(); BAR(); SB();
  }
#undef STGB
#undef STGA
#undef RD
#undef MM16

  const int c0 = bn + wn * 64 + lr;
  if (BF16_OUT) {
    unsigned short* C = (unsigned short*)Cout;
    #pragma unroll
    for (int fi = 0; fi < 4; ++fi)
      #pragma unroll
      for (int i = 0; i < 4; ++i) {
        size_t r = (size_t)(bm + wm * 64 + fi * 16 + lq * 4 + i);
        #pragma unroll
        for (int nf = 0; nf < 4; ++nf)
          C[r * ldc + c0 + (nf >> 1) * 32 + (nf & 1) * 16] = f2bf(acc[fi][nf][i]);
      }
  } else {
    float* C = (float*)Cout;
    float bv[4];
    #pragma unroll
    for (int nf = 0; nf < 4; ++nf)
      bv[nf] = bias ? bias[c0 + (nf >> 1) * 32 + (nf & 1) * 16] : 0.f;
    #pragma unroll
    for (int fi = 0; fi < 4; ++fi)
      #pragma unroll
      for (int i = 0; i < 4; ++i) {
        size_t r = (size_t)(bm + wm * 64 + fi * 16 + lq * 4 + i);
        #pragma unroll
        for (int nf = 0; nf < 4; ++nf)
          C[r * ldc + c0 + (nf >> 1) * 32 + (nf & 1) * 16] = acc[fi][nf][i] + bv[nf];
      }
  }
}

// --------------------------------- partial M^T = scale*(k^T v)^T over j ----
__global__ __launch_bounds__(256) void kv_outer(
    const unsigned short* __restrict__ qkv,
    unsigned short* __restrict__ MT, float scale) {
  const int bid = blockIdx.x;
  const int p = bid & 3, unit = bid >> 2;
  const int b = unit >> 5, h = (unit >> 1) & 15, hf = unit & 1;
  const size_t base = ((size_t)(b * 2048 + hf * 1024)) * 3072 + h * 64;
  const unsigned short* kp = qkv + base + 1024;
  const unsigned short* vp = qkv + base + 2048;
  __shared__ __align__(16) unsigned short kT[64][136];
  __shared__ __align__(16) unsigned short vT[64][136];
  const int tid = threadIdx.x, wv = tid >> 6, ln = tid & 63;
  f32x4 acc[4] = {};
  const int e4 = (tid & 15) * 4;
  const int jr = tid >> 4;
  const int fr = ln & 15, ko = (ln >> 4) * 8;

  for (int j0 = p * 256; j0 < p * 256 + 256; j0 += 128) {
    __syncthreads();
    #pragma unroll
    for (int jj = 0; jj < 128; jj += 16) {
      int j = jj + jr;
      size_t go = (size_t)(j0 + j) * 3072 + e4;
      short4v k4 = *(const short4v*)(kp + go);
      short4v v4 = *(const short4v*)(vp + go);
      #pragma unroll
      for (int t = 0; t < 4; t++) {
        kT[e4 + t][j] = (unsigned short)k4[t];
        vT[e4 + t][j] = (unsigned short)v4[t];
      }
    }
    __syncthreads();
    #pragma unroll
    for (int kk = 0; kk < 128; kk += 32) {
      bf16x8 af = *(const bf16x8*)&kT[wv * 16 + fr][kk + ko];
      #pragma unroll
      for (int n = 0; n < 4; n++) {
        bf16x8 bf2 = *(const bf16x8*)&vT[n * 16 + fr][kk + ko];
        acc[n] = __builtin_amdgcn_mfma_f32_16x16x32_bf16(af, bf2, acc[n], 0, 0, 0);
      }
    }
  }
  unsigned short* outp = MT + (size_t)bid * 4096;       // [d][e], 64x64
  #pragma unroll
  for (int n = 0; n < 4; n++)
    #pragma unroll
    for (int i = 0; i < 4; i++) {
      int d = n * 16 + fr;
      int e = wv * 16 + (ln >> 4) * 4 + i;
      outp[d * 64 + e] = f2bf(acc[n][i] * scale);
    }
}

// ---------------- W2T[g][:, h-block] = wprojT[:, h-block] @ M_h (64x64) ----
__global__ __launch_bounds__(256) void w2k(
    const unsigned short* __restrict__ MTp,
    const unsigned short* __restrict__ wprojT,
    unsigned short* __restrict__ w2t) {
  const int g = blockIdx.x >> 4, h = blockIdx.x & 15;
  const int b = g >> 1, hfq = g & 1;
  const int unit = b * 32 + h * 2 + (1 - hfq);
  const unsigned short* mp = MTp + (size_t)(unit * 4) * 4096;
  __shared__ unsigned short Ms[64][72];     // Ms[e][d] = sum_p M^T_p[d][e]
  const int tid = threadIdx.x;
  {
    const int d = tid >> 2, eb = (tid & 3) * 16;
    #pragma unroll
    for (int j = 0; j < 16; ++j) {
      float s = 0.f;
      #pragma unroll
      for (int p = 0; p < 4; ++p)
        s += bf2f(mp[p * 4096 + d * 64 + eb + j]);
      Ms[eb + j][d] = f2bf(s);
    }
  }
  __syncthreads();
  const int w = tid >> 6, ln = tid & 63;
  const int fr = ln & 15, lq = ln >> 4, ko = lq * 8;
  bf16x8 bb[4][2];
  #pragma unroll
  for (int nf = 0; nf < 4; ++nf)
    #pragma unroll
    for (int ks = 0; ks < 2; ++ks)
      bb[nf][ks] = *(const bf16x8*)&Ms[nf * 16 + fr][ks * 32 + ko];
  const unsigned short* ap = wprojT + h * 64;
  unsigned short* op = w2t + (size_t)g * 1048576 + h * 64;
  #pragma unroll 4
  for (int cf = 0; cf < 16; ++cf) {
    const int crow = w * 256 + cf * 16;
    f32x4 acc[4] = {};
    #pragma unroll
    for (int ks = 0; ks < 2; ++ks) {
      bf16x8 a = *(const bf16x8*)(ap + (size_t)(crow + fr) * 1024 + ks * 32 + ko);
      #pragma unroll
      for (int nf = 0; nf < 4; ++nf)
        acc[nf] = __builtin_amdgcn_mfma_f32_16x16x32_bf16(a, bb[nf][ks], acc[nf], 0, 0, 0);
    }
    #pragma unroll
    for (int nf = 0; nf < 4; ++nf)
      #pragma unroll
      for (int i = 0; i < 4; ++i)
        op[(size_t)(crow + lq * 4 + i) * 1024 + nf * 16 + fr] = f2bf(acc[nf][i]);
  }
}

// ---------------------------------------------------------------------------
extern "C" void kernel_launch(void* const* d_in, const int* in_sizes, int n_in,
                              void* d_out, int out_size, void* d_ws, size_t ws_size,
                              hipStream_t stream) {
  const float* x     = (const float*)d_in[0];   // 4 x 2048 x 1024
  const float* Wqkv  = (const float*)d_in[1];   // 1024 x 3072
  const float* Wproj = (const float*)d_in[2];   // 1024 x 1024
  const float* bproj = (const float*)d_in[3];   // 1024
  float* out = (float*)d_out;                   // 8192 x 1024

  char* ws = (char*)d_ws;
  unsigned short* xb     = (unsigned short*)(ws);               // 16.78 MB (dead after v-GEMM)
  unsigned short* W2T    = (unsigned short*)(ws);               // 16.0 MB, aliases xb
  unsigned short* wqkvT  = (unsigned short*)(ws + 16777216);    //  6.29 MB
  unsigned short* wprojT = (unsigned short*)(ws + 23068672);    //  2.10 MB
  unsigned short* qkv    = (unsigned short*)(ws + 25165824);    // 50.33 MB
  unsigned short* MT     = (unsigned short*)(ws + 75497472);    //  2.10 MB

  // fused cast + weight transposes
  prep<<<12288, 256, 0, stream>>>(x, Wqkv, Wproj, xb, wqkvT, wprojT);

  // qk = x @ W_qkv[:, :2048] -> qkv cols 0..2047.
  // gemm128 shape: grid 8x64 = 512 blocks = 2 exact full-chip rounds.
  gemm128<1><<<dim3(8, 64), 512, 0, stream>>>(xb, 1024, wqkvT, 0,
                                              (void*)qkv, nullptr, 3072, 1024);
  // v = x @ W_qkv[:, 2048:] -> qkv cols 2048..3071.  grid 4x64 = 256 exact.
  gemm128<1><<<dim3(4, 64), 512, 0, stream>>>(xb, 1024,
                                              wqkvT + (size_t)2048 * 1024, 0,
                                              (void*)(qkv + 2048), nullptr,
                                              3072, 1024);

  // partial M^T per (b,h,half, j-quarter) — 512 blocks
  kv_outer<<<512, 256, 0, stream>>>(qkv, MT, 0.125f);

  // W2T[g] = wprojT @ blockdiag(M_g)  — 128 blocks (g,h)
  w2k<<<128, 256, 0, stream>>>(MT, wprojT, W2T);

  // out = q @ W2T[group]^T + b  (fp32), q read in place (lda=3072).
  // grid 4x64 = 256 exact; groups are 1024-row aligned (8 tiles/group).
  gemm128<0><<<dim3(4, 64), 512, 0, stream>>>(qkv, 3072,
                                              W2T, (size_t)1048576,
                                              (void*)out, bproj,
                                              1024, 1024);
}

// Round 13
// 122.945 us; speedup vs baseline: 1.0745x; 1.0745x over previous
//
#include <hip/hip_runtime.h>
#include <stdint.h>

typedef __attribute__((ext_vector_type(8))) short  bf16x8;
typedef __attribute__((ext_vector_type(4))) short  short4v;
typedef __attribute__((ext_vector_type(4))) float  f32x4;
typedef __attribute__((ext_vector_type(4))) float  float4v;

__device__ __forceinline__ unsigned short f2bf(float f) {
  unsigned int u = __builtin_bit_cast(unsigned int, f);
  u += 0x7FFFu + ((u >> 16) & 1u);          // round-to-nearest-even
  return (unsigned short)(u >> 16);
}
__device__ __forceinline__ float bf2f(unsigned short u) {
  return __builtin_bit_cast(float, (unsigned int)u << 16);
}

__device__ __forceinline__ void async_ld16(const void* g, void* l) {
  __builtin_amdgcn_global_load_lds(
      (const __attribute__((address_space(1))) void*)g,
      (__attribute__((address_space(3))) void*)l,
      16, 0, 0);
}

#define SB()  __builtin_amdgcn_sched_barrier(0)
#define BAR() __builtin_amdgcn_s_barrier()

// ----------------------------------------------------------- fused prep ----
__global__ __launch_bounds__(256) void prep(
    const float* __restrict__ x, const float* __restrict__ Wqkv,
    const float* __restrict__ Wproj,
    unsigned short* __restrict__ xb, unsigned short* __restrict__ wqkvT,
    unsigned short* __restrict__ wprojT) {
  __shared__ float tile[32][33];
  const int b = blockIdx.x, tid = threadIdx.x;
  if (b < 8192) {
    int i = b * 256 + tid;
    float4v v = *(const float4v*)(x + (size_t)i * 4);
    short4v o;
    o[0] = (short)f2bf(v[0]); o[1] = (short)f2bf(v[1]);
    o[2] = (short)f2bf(v[2]); o[3] = (short)f2bf(v[3]);
    *(short4v*)(xb + (size_t)i * 4) = o;
    return;
  }
  const float* in; unsigned short* out; int R, C, bx, by;
  if (b < 11264) { int t = b - 8192;  in = Wqkv;  out = wqkvT;  R = 1024; C = 3072; bx = t % 96; by = t / 96; }
  else           { int t = b - 11264; in = Wproj; out = wprojT; R = 1024; C = 1024; bx = t & 31; by = t >> 5; }
  const int tx = tid & 31, ty = tid >> 5;
  const int c0 = bx * 32, r0 = by * 32;
  #pragma unroll
  for (int rr = ty; rr < 32; rr += 8)
    tile[rr][tx] = in[(size_t)(r0 + rr) * C + c0 + tx];
  __syncthreads();
  #pragma unroll
  for (int cc = ty; cc < 32; cc += 8)
    out[(size_t)(c0 + cc) * R + r0 + tx] = f2bf(tile[tx][cc]);
}

// ---------------- 8-phase 256^2 GEMM, 5 barriers/tile (R9 measured-best) ----
// C[M,N] = A*BT^T.  512 thr, 8 waves (2M x 4N), wave 128x64, BK=64.
// Reads spread 12/4/8/0; staging 1 panel/phase; end-of-tile vmcnt(4).
template<int BF16_OUT>
__global__ __launch_bounds__(512, 2) void gemm8t(
    const unsigned short* __restrict__ A,
    const unsigned short* __restrict__ BT,
    void* __restrict__ Cout, const float* __restrict__ bias,
    int ldc, int K) {
  constexpr int PAN = 16384;
  __shared__ __align__(16) char lds[8 * PAN];      // 128 KiB
  const int tid = threadIdx.x;
  const int ln = tid & 63, w = tid >> 6;
  const int lr = ln & 15, lq = ln >> 4;
  const int wm = w >> 2, wn = w & 3;

  int wid = blockIdx.y * gridDim.x + blockIdx.x;
  const int nwg = gridDim.x * gridDim.y;
  { const int q = nwg >> 3; wid = (wid & 7) * q + (wid >> 3); }
  const int bm = (wid / gridDim.x) * 256, bn = (wid % gridDim.x) * 256;

  const int srow = tid >> 3;
  const int csw = ((tid & 7) ^ (srow & 7)) * 8;
  const unsigned short* rB0 = BT + (size_t)(bn + srow) * K + csw;
  const unsigned short* rB1 = rB0 + (size_t)128 * K;
  const unsigned short* rA0 = A  + (size_t)(bm + srow) * K + csw;
  const unsigned short* rA1 = rA0 + (size_t)128 * K;
  const size_t rowL1 = (size_t)64 * K;
  char* ldst = lds + tid * 16;

#define STG(slot, src, t) do {                                               \
    async_ld16((src) + (size_t)(t) * 64,         ldst + (slot) * PAN);       \
    async_ld16((src) + (size_t)(t) * 64 + rowL1, ldst + (slot) * PAN + 8192);\
  } while (0)

  const int sw0 = ((0 + lq) ^ (lr & 7)) * 16;
  const int sw1 = ((4 + lq) ^ (lr & 7)) * 16;
  const char* Bbase = lds + ((wn & 1) * 64 + lr) * 128;
  const char* Abase = lds + lr * 128;

  bf16x8 a[4][2], b[4][2];
  f32x4 acc[8][4] = {};

#define READ_B2(Bp, nh)                                                      \
    _Pragma("unroll")                                                        \
    for (int bj = 0; bj < 2; ++bj) {                                         \
      const char* p_ = (Bp) + (nh) * 4096 + bj * 2048;                       \
      b[(nh) * 2 + bj][0] = *(const bf16x8*)(p_ + sw0);                      \
      b[(nh) * 2 + bj][1] = *(const bf16x8*)(p_ + sw1);                      \
    }
#define READ_A(Ap)                                                           \
    _Pragma("unroll")                                                        \
    for (int fi = 0; fi < 4; ++fi) {                                         \
      const char* p_ = (Ap) + fi * 2048;                                     \
      a[fi][0] = *(const bf16x8*)(p_ + sw0);                                 \
      a[fi][1] = *(const bf16x8*)(p_ + sw1);                                 \
    }
#define MFMA16(mh, nh)                                                       \
    __builtin_amdgcn_s_setprio(1);                                           \
    _Pragma("unroll")                                                        \
    for (int fi = 0; fi < 4; ++fi)                                           \
      _Pragma("unroll")                                                      \
      for (int bj = 0; bj < 2; ++bj) {                                       \
        f32x4 t_ = acc[(mh) * 4 + fi][(nh) * 2 + bj];                        \
        t_ = __builtin_amdgcn_mfma_f32_16x16x32_bf16(a[fi][0], b[(nh)*2+bj][0], t_, 0, 0, 0); \
        t_ = __builtin_amdgcn_mfma_f32_16x16x32_bf16(a[fi][1], b[(nh)*2+bj][1], t_, 0, 0, 0); \
        acc[(mh) * 4 + fi][(nh) * 2 + bj] = t_;                              \
      }                                                                      \
    __builtin_amdgcn_s_setprio(0);

  const int NT = K / 64;

  // prologue: tile0 complete (slots 0..3) + tile1 B panels (slots 4,5)
  STG(0, rB0, 0); STG(1, rB1, 0); STG(2, rA0, 0); STG(3, rA1, 0);
  STG(4, rB0, 1); STG(5, rB1, 1);
  asm volatile("s_waitcnt vmcnt(4)" ::: "memory");
  SB(); BAR(); SB();

  for (int t = 0; t < NT; ++t) {
    const int par = (t & 1) * 4, opar = ((t + 1) & 1) * 4;
    const char* Ap = Abase + (size_t)(par + 2 + wm) * PAN;
    const char* Bp = Bbase + (size_t)(par + (wn >> 1)) * PAN;
    // ---- phase 0: reads B-half0 + A-mh0; stage A0(t+1); open MFMA ----
    READ_B2(Bp, 0);
    READ_A(Ap);
    if (t + 1 < NT) STG(opar + 2, rA0, t + 1);
    SB(); BAR();
    asm volatile("s_waitcnt lgkmcnt(0)" ::: "memory");
    SB();
    MFMA16(0, 0);
    // ---- phase 1: reads B-half1; stage A1(t+1); open MFMA ----
    READ_B2(Bp, 1);
    if (t + 1 < NT) STG(opar + 3, rA1, t + 1);
    SB(); BAR();
    asm volatile("s_waitcnt lgkmcnt(0)" ::: "memory");
    SB();
    MFMA16(0, 1);
    // ---- phase 2: reads A-mh1; stage B0(t+2); open MFMA ----
    READ_A(Ap + 8192);
    if (t + 2 < NT) STG(par + 0, rB0, t + 2);
    SB(); BAR();
    asm volatile("s_waitcnt lgkmcnt(0)" ::: "memory");
    SB();
    MFMA16(1, 0);
    // ---- phase 3: stage B1(t+2); MFMA; counted drain + publish ----
    if (t + 2 < NT) STG(par + 1, rB1, t + 2);
    SB(); BAR(); SB();
    MFMA16(1, 1);
    if (t < NT - 2)       asm volatile("s_waitcnt vmcnt(4)" ::: "memory");
    else if (t == NT - 2) asm volatile("s_waitcnt vmcnt(0)" ::: "memory");
    SB(); BAR(); SB();
  }
#undef STG
#undef READ_B2
#undef READ_A
#undef MFMA16

  const int c0 = bn + wn * 64 + lr;
  if (BF16_OUT) {
    unsigned short* C = (unsigned short*)Cout;
    #pragma unroll
    for (int mf = 0; mf < 8; ++mf)
      #pragma unroll
      for (int i = 0; i < 4; ++i) {
        size_t r = (size_t)(bm + wm * 128 + (mf >> 2) * 64 + (mf & 3) * 16 + lq * 4 + i);
        #pragma unroll
        for (int nf = 0; nf < 4; ++nf)
          C[r * ldc + c0 + (nf >> 1) * 32 + (nf & 1) * 16] = f2bf(acc[mf][nf][i]);
      }
  } else {
    float* C = (float*)Cout;
    float bv[4];
    #pragma unroll
    for (int nf = 0; nf < 4; ++nf)
      bv[nf] = bias ? bias[c0 + (nf >> 1) * 32 + (nf & 1) * 16] : 0.f;
    #pragma unroll
    for (int mf = 0; mf < 8; ++mf)
      #pragma unroll
      for (int i = 0; i < 4; ++i) {
        size_t r = (size_t)(bm + wm * 128 + (mf >> 2) * 64 + (mf & 3) * 16 + lq * 4 + i);
        #pragma unroll
        for (int nf = 0; nf < 4; ++nf)
          C[r * ldc + c0 + (nf >> 1) * 32 + (nf & 1) * 16] = acc[mf][nf][i] + bv[nf];
      }
  }
}

// ------------------- 128x256-tile variant, 3 barriers/tile (grouped-B) -----
// C[M,N] = A[M,K](lda) * BTg[N,K]^T where BTg = BT + (bm>>10)*gstride.
template<int BF16_OUT>
__global__ __launch_bounds__(512, 1) void gemm128(
    const unsigned short* __restrict__ A, int lda,
    const unsigned short* __restrict__ BT, size_t gstride,
    void* __restrict__ Cout, const float* __restrict__ bias,
    int ldc, int K) {
  constexpr int PAN = 16384;
  __shared__ __align__(16) char lds[6 * PAN];      // 96 KiB
  const int tid = threadIdx.x;
  const int ln = tid & 63, w = tid >> 6;
  const int lr = ln & 15, lq = ln >> 4;
  const int wm = w >> 2, wn = w & 3;

  int wid = blockIdx.y * gridDim.x + blockIdx.x;
  const int nwg = gridDim.x * gridDim.y;
  { const int q = nwg >> 3; wid = (wid & 7) * q + (wid >> 3); }
  const int bm = (wid / gridDim.x) * 128, bn = (wid % gridDim.x) * 256;

  const int srow = tid >> 3;
  const int csw = ((tid & 7) ^ (srow & 7)) * 8;
  const unsigned short* BTg = BT + (size_t)(bm >> 10) * gstride;
  const unsigned short* rB0 = BTg + (size_t)(bn + srow) * K + csw;
  const unsigned short* rB1 = rB0 + (size_t)128 * K;
  const unsigned short* rA0 = A + (size_t)(bm + srow) * lda + csw;
  const size_t rowB = (size_t)64 * K;
  const size_t rowA = (size_t)64 * lda;
  char* ldst = lds + tid * 16;

#define STGB(slot, src, t) do {                                              \
    async_ld16((src) + (size_t)(t) * 64,        ldst + (slot) * PAN);        \
    async_ld16((src) + (size_t)(t) * 64 + rowB, ldst + (slot) * PAN + 8192); \
  } while (0)
#define STGA(slot, src, t) do {                                              \
    async_ld16((src) + (size_t)(t) * 64,        ldst + (slot) * PAN);        \
    async_ld16((src) + (size_t)(t) * 64 + rowA, ldst + (slot) * PAN + 8192); \
  } while (0)

  const int sw0 = ((0 + lq) ^ (lr & 7)) * 16;
  const int sw1 = ((4 + lq) ^ (lr & 7)) * 16;
  const char* Arow = lds + (wm * 64 + lr) * 128;
  const char* Brow = lds + ((wn & 1) * 64 + lr) * 128;

  bf16x8 a[4], b[4];
  f32x4 acc[4][4] = {};

#define RD(ph_sw, Ap, Bp)                                                    \
    _Pragma("unroll")                                                        \
    for (int nf = 0; nf < 4; ++nf) b[nf] = *(const bf16x8*)((Bp) + nf * 2048 + (ph_sw)); \
    _Pragma("unroll")                                                        \
    for (int fi = 0; fi < 4; ++fi) a[fi] = *(const bf16x8*)((Ap) + fi * 2048 + (ph_sw));
#define MM16()                                                               \
    __builtin_amdgcn_s_setprio(1);                                           \
    _Pragma("unroll")                                                        \
    for (int fi = 0; fi < 4; ++fi)                                           \
      _Pragma("unroll")                                                      \
      for (int nf = 0; nf < 4; ++nf)                                         \
        acc[fi][nf] = __builtin_amdgcn_mfma_f32_16x16x32_bf16(a[fi], b[nf], acc[fi][nf], 0, 0, 0); \
    __builtin_amdgcn_s_setprio(0);

  STGB(0, rB0, 0); STGB(1, rB1, 0); STGA(2, rA0, 0);
  STGB(3, rB0, 1); STGB(4, rB1, 1); STGA(5, rA0, 1);
  asm volatile("s_waitcnt vmcnt(6)" ::: "memory");
  SB(); BAR(); SB();

  const int NT = K / 64;
  for (int t = 0; t < NT; ++t) {
    const int par = (t & 1) * 3;
    const char* Ap = Arow + (par + 2) * PAN;
    const char* Bp = Brow + (par + (wn >> 1)) * PAN;
    RD(sw0, Ap, Bp);
    SB(); BAR();
    asm volatile("s_waitcnt lgkmcnt(0)" ::: "memory");
    SB();
    MM16();
    RD(sw1, Ap, Bp);
    SB(); BAR();
    asm volatile("s_waitcnt lgkmcnt(0)" ::: "memory");
    SB();
    MM16();
    if (t + 2 < NT) {
      STGB(par + 0, rB0, t + 2); STGB(par + 1, rB1, t + 2); STGA(par + 2, rA0, t + 2);
      asm volatile("s_waitcnt vmcnt(6)" ::: "memory");
    } else if (t == NT - 2) {
      asm volatile("s_waitcnt vmcnt(0)" ::: "memory");
    }
    SB(); BAR(); SB();
  }
#undef STGB
#undef STGA
#undef RD
#undef MM16

  const int c0 = bn + wn * 64 + lr;
  if (BF16_OUT) {
    unsigned short* C = (unsigned short*)Cout;
    #pragma unroll
    for (int fi = 0; fi < 4; ++fi)
      #pragma unroll
      for (int i = 0; i < 4; ++i) {
        size_t r = (size_t)(bm + wm * 64 + fi * 16 + lq * 4 + i);
        #pragma unroll
        for (int nf = 0; nf < 4; ++nf)
          C[r * ldc + c0 + (nf >> 1) * 32 + (nf & 1) * 16] = f2bf(acc[fi][nf][i]);
      }
  } else {
    float* C = (float*)Cout;
    float bv[4];
    #pragma unroll
    for (int nf = 0; nf < 4; ++nf)
      bv[nf] = bias ? bias[c0 + (nf >> 1) * 32 + (nf & 1) * 16] : 0.f;
    #pragma unroll
    for (int fi = 0; fi < 4; ++fi)
      #pragma unroll
      for (int i = 0; i < 4; ++i) {
        size_t r = (size_t)(bm + wm * 64 + fi * 16 + lq * 4 + i);
        #pragma unroll
        for (int nf = 0; nf < 4; ++nf)
          C[r * ldc + c0 + (nf >> 1) * 32 + (nf & 1) * 16] = acc[fi][nf][i] + bv[nf];
      }
  }
}

// ------------------ partial M^T = scale*(k^T v)^T over j, 8-way split ------
// block = unit*8 + p ; unit = b*32 + h*2 + half ; p = j-eighth (128 rows)
__global__ __launch_bounds__(256) void kv_outer(
    const unsigned short* __restrict__ qkv,
    unsigned short* __restrict__ MT, float scale) {
  const int bid = blockIdx.x;
  const int p = bid & 7, unit = bid >> 3;
  const int b = unit >> 5, h = (unit >> 1) & 15, hf = unit & 1;
  const size_t base = ((size_t)(b * 2048 + hf * 1024)) * 3072 + h * 64;
  const unsigned short* kp = qkv + base + 1024;
  const unsigned short* vp = qkv + base + 2048;
  __shared__ __align__(16) unsigned short kT[64][136];
  __shared__ __align__(16) unsigned short vT[64][136];
  const int tid = threadIdx.x, wv = tid >> 6, ln = tid & 63;
  f32x4 acc[4] = {};
  const int e4 = (tid & 15) * 4;
  const int jr = tid >> 4;
  const int fr = ln & 15, ko = (ln >> 4) * 8;

  const int j0 = p * 128;
  {
    #pragma unroll
    for (int jj = 0; jj < 128; jj += 16) {
      int j = jj + jr;
      size_t go = (size_t)(j0 + j) * 3072 + e4;
      short4v k4 = *(const short4v*)(kp + go);
      short4v v4 = *(const short4v*)(vp + go);
      #pragma unroll
      for (int t = 0; t < 4; t++) {
        kT[e4 + t][j] = (unsigned short)k4[t];
        vT[e4 + t][j] = (unsigned short)v4[t];
      }
    }
    __syncthreads();
    #pragma unroll
    for (int kk = 0; kk < 128; kk += 32) {
      bf16x8 af = *(const bf16x8*)&kT[wv * 16 + fr][kk + ko];
      #pragma unroll
      for (int n = 0; n < 4; n++) {
        bf16x8 bf2 = *(const bf16x8*)&vT[n * 16 + fr][kk + ko];
        acc[n] = __builtin_amdgcn_mfma_f32_16x16x32_bf16(af, bf2, acc[n], 0, 0, 0);
      }
    }
  }
  unsigned short* outp = MT + (size_t)bid * 4096;       // [d][e], 64x64
  #pragma unroll
  for (int n = 0; n < 4; n++)
    #pragma unroll
    for (int i = 0; i < 4; i++) {
      int d = n * 16 + fr;
      int e = wv * 16 + (ln >> 4) * 4 + i;
      outp[d * 64 + e] = f2bf(acc[n][i] * scale);
    }
}

// ---------------- W2T[g][:, h-block] = wprojT[:, h-block] @ M_h (64x64) ----
// g = b*2 + hf_q consumes unit = b*32 + h*2 + (1-hf_q); sums 8 partials.
__global__ __launch_bounds__(256) void w2k(
    const unsigned short* __restrict__ MTp,
    const unsigned short* __restrict__ wprojT,
    unsigned short* __restrict__ w2t) {
  const int g = blockIdx.x >> 4, h = blockIdx.x & 15;
  const int b = g >> 1, hfq = g & 1;
  const int unit = b * 32 + h * 2 + (1 - hfq);
  const unsigned short* mp = MTp + (size_t)(unit * 8) * 4096;
  __shared__ unsigned short Ms[64][72];     // Ms[e][d] = sum_p M^T_p[d][e]
  const int tid = threadIdx.x;
  {
    const int d = tid >> 2, eb = (tid & 3) * 16;
    #pragma unroll
    for (int j = 0; j < 16; ++j) {
      float s = 0.f;
      #pragma unroll
      for (int p = 0; p < 8; ++p)
        s += bf2f(mp[p * 4096 + d * 64 + eb + j]);
      Ms[eb + j][d] = f2bf(s);
    }
  }
  __syncthreads();
  const int w = tid >> 6, ln = tid & 63;
  const int fr = ln & 15, lq = ln >> 4, ko = lq * 8;
  bf16x8 bb[4][2];
  #pragma unroll
  for (int nf = 0; nf < 4; ++nf)
    #pragma unroll
    for (int ks = 0; ks < 2; ++ks)
      bb[nf][ks] = *(const bf16x8*)&Ms[nf * 16 + fr][ks * 32 + ko];
  const unsigned short* ap = wprojT + h * 64;
  unsigned short* op = w2t + (size_t)g * 1048576 + h * 64;
  #pragma unroll 4
  for (int cf = 0; cf < 16; ++cf) {
    const int crow = w * 256 + cf * 16;
    f32x4 acc[4] = {};
    #pragma unroll
    for (int ks = 0; ks < 2; ++ks) {
      bf16x8 a = *(const bf16x8*)(ap + (size_t)(crow + fr) * 1024 + ks * 32 + ko);
      #pragma unroll
      for (int nf = 0; nf < 4; ++nf)
        acc[nf] = __builtin_amdgcn_mfma_f32_16x16x32_bf16(a, bb[nf][ks], acc[nf], 0, 0, 0);
    }
    #pragma unroll
    for (int nf = 0; nf < 4; ++nf)
      #pragma unroll
      for (int i = 0; i < 4; ++i)
        op[(size_t)(crow + lq * 4 + i) * 1024 + nf * 16 + fr] = f2bf(acc[nf][i]);
  }
}

// ---------------------------------------------------------------------------
extern "C" void kernel_launch(void* const* d_in, const int* in_sizes, int n_in,
                              void* d_out, int out_size, void* d_ws, size_t ws_size,
                              hipStream_t stream) {
  const float* x     = (const float*)d_in[0];   // 4 x 2048 x 1024
  const float* Wqkv  = (const float*)d_in[1];   // 1024 x 3072
  const float* Wproj = (const float*)d_in[2];   // 1024 x 1024
  const float* bproj = (const float*)d_in[3];   // 1024
  float* out = (float*)d_out;                   // 8192 x 1024

  char* ws = (char*)d_ws;
  unsigned short* xb     = (unsigned short*)(ws);               // 16.78 MB (dead after v-GEMM)
  unsigned short* W2T    = (unsigned short*)(ws);               // 16.0 MB, aliases xb
  unsigned short* wqkvT  = (unsigned short*)(ws + 16777216);    //  6.29 MB
  unsigned short* wprojT = (unsigned short*)(ws + 23068672);    //  2.10 MB
  unsigned short* qkv    = (unsigned short*)(ws + 25165824);    // 50.33 MB
  unsigned short* MT     = (unsigned short*)(ws + 75497472);    //  8.39 MB (1024 x 4096 bf16)
  // total 83.9 MB

  // fused cast + weight transposes
  prep<<<12288, 256, 0, stream>>>(x, Wqkv, Wproj, xb, wqkvT, wprojT);

  // qk = x @ W_qkv[:, :2048] -> qkv cols 0..2047.  grid 8x32 = 256 exact.
  gemm8t<1><<<dim3(8, 32), 512, 0, stream>>>(xb, wqkvT, (void*)qkv, nullptr,
                                             3072, 1024);
  // v = x @ W_qkv[:, 2048:] -> qkv cols 2048..3071.  grid 4x64 = 256 exact.
  gemm128<1><<<dim3(4, 64), 512, 0, stream>>>(xb, 1024,
                                              wqkvT + (size_t)2048 * 1024, 0,
                                              (void*)(qkv + 2048), nullptr,
                                              3072, 1024);

  // partial M^T per (b,h,half, j-eighth) — 1024 blocks (4/CU)
  kv_outer<<<1024, 256, 0, stream>>>(qkv, MT, 0.125f);

  // W2T[g] = wprojT @ blockdiag(M_g)  — 128 blocks (g,h), sums 8 partials
  w2k<<<128, 256, 0, stream>>>(MT, wprojT, W2T);

  // out = q @ W2T[group]^T + b  (fp32), q read in place (lda=3072).
  // grid 4x64 = 256 exact; groups are 1024-row aligned (8 tiles/group).
  gemm128<0><<<dim3(4, 64), 512, 0, stream>>>(qkv, 3072,
                                              W2T, (size_t)1048576,
                                              (void*)out, bproj,
                                              1024, 1024);
}